// Round 5
// baseline (101.464 us; speedup 1.0000x reference)
//
#include <hip/hip_runtime.h>
#include <math.h>

// SimpleMamba: s_t = A*s_{t-1} + B*x_t ; y_t = tanh(C*s_t), per-channel.
// L=8192, D=2048, f32.
//
// R5 (= R4 + compile fix): single persistent-grid fused kernel. Each thread owns
// one (chunk, f4-group), holds its 32 float4 of x in REGISTERS across a
// hand-rolled device-scope grid barrier -> x read from memory exactly once.
// Co-residency: 512 blocks x 256 thr = 2 blocks/CU exactly; __launch_bounds__(256,2)
// caps VGPR at 256 -> 8 waves/CU -> guaranteed resident.
// CL=32 pinned by f32 overflow (A^32 finite for max|A|~3.9; A^64 would overflow).
// Scan stays a flat serial chain (tree compose is inf-inf NaN-unsafe for |A|>1).

#define LL 8192
#define DD 2048
#define CL 32
#define NC (LL / CL)          // 256 chunks
#define G4 (DD / 4)           // 512 float4 channel-groups
#define NBLK (NC * G4 / 256)  // 512 blocks
#define NSCAN (DD / 256)      // 8 scan blocks (2048 scan threads, 1/channel)

typedef float f32x4 __attribute__((ext_vector_type(4)));  // native vec for nontemporal store

__device__ __forceinline__ float fast_tanh(float z)
{
    // tanh(z) = 1 - 2/(exp2(2z*log2e)+1); exact saturation at +-inf, ~1e-7 err.
    float e = __builtin_amdgcn_exp2f(z * 2.885390081777927f);
    return 1.0f - 2.0f * __builtin_amdgcn_rcpf(e + 1.0f);
}

// ==================== fused persistent kernel ====================
__global__ __launch_bounds__(256, 2) void mamba_fused(
    const float4* __restrict__ x4, const float4* __restrict__ A4,
    const float4* __restrict__ B4, const float4* __restrict__ C4,
    float4* __restrict__ loc4, float4* __restrict__ car4,
    unsigned* __restrict__ cnt, float4* __restrict__ y4)
{
    const int lin   = blockIdx.x * 256 + threadIdx.x;
    const int chunk = lin >> 9;          // / G4
    const int grp   = lin & (G4 - 1);

    const float4 a = A4[grp];
    const float4 b = B4[grp];

    const size_t base = (size_t)chunk * CL * G4 + grp;

    // ---- load this thread's x chunk into registers (32 x dwordx4 in flight) ----
    float4 xr[CL];
    #pragma unroll
    for (int t = 0; t < CL; ++t) xr[t] = x4[base + (size_t)t * G4];

    // ---- phase A: chunk-local end state from s=0 ----
    float sx = 0.f, sy = 0.f, sz = 0.f, sw = 0.f;
    #pragma unroll
    for (int t = 0; t < CL; ++t) {
        sx = fmaf(a.x, sx, b.x * xr[t].x);
        sy = fmaf(a.y, sy, b.y * xr[t].y);
        sz = fmaf(a.z, sz, b.z * xr[t].z);
        sw = fmaf(a.w, sw, b.w * xr[t].w);
    }
    loc4[(size_t)chunk * G4 + grp] = make_float4(sx, sy, sz, sw);

    // ---- barrier 1 arrive (wait-free for everyone) ----
    __syncthreads();                       // drains vmcnt: block's loc stores are in L2
    if (threadIdx.x == 0) {
        __threadfence();                   // release: write back to coherent point
        __hip_atomic_fetch_add(&cnt[0], 1u, __ATOMIC_RELAXED, __HIP_MEMORY_SCOPE_AGENT);
    }

    // ---- phase B: 8 scan blocks do the serial carry chain ----
    if (blockIdx.x < NSCAN) {
        if (threadIdx.x == 0) {
            while (__hip_atomic_load(&cnt[0], __ATOMIC_RELAXED, __HIP_MEMORY_SCOPE_AGENT) < NBLK)
                __builtin_amdgcn_s_sleep(2);
            __threadfence();               // acquire: inv L1/L2 -> fresh loc
        }
        __syncthreads();

        const int ch = blockIdx.x * 256 + threadIdx.x;   // 0..DD-1
        const float* loc = (const float*)loc4;
        float*       car = (float*)car4;

        float p = ((const float*)A4)[ch];  // A^32 via 5 squarings (finite)
        #pragma unroll
        for (int i = 0; i < 5; ++i) p *= p;

        float c = 0.f;
        for (int c0 = 0; c0 < NC; c0 += 32) {
            float lv[32];
            #pragma unroll
            for (int k = 0; k < 32; ++k)
                lv[k] = loc[(size_t)(c0 + k) * DD + ch];    // 32 loads in flight
            #pragma unroll
            for (int k = 0; k < 32; ++k) {
                car[(size_t)(c0 + k) * DD + ch] = c;
                c = fmaf(p, c, lv[k]);     // lv finite -> no inf-inf NaN
            }
        }

        __syncthreads();                   // drain car stores to L2
        if (threadIdx.x == 0) {
            __threadfence();               // release car
            __hip_atomic_fetch_add(&cnt[1], 1u, __ATOMIC_RELAXED, __HIP_MEMORY_SCOPE_AGENT);
        }
    }

    // ---- barrier 2 wait (everyone; only scan blocks increment cnt[1]) ----
    if (threadIdx.x == 0) {
        while (__hip_atomic_load(&cnt[1], __ATOMIC_RELAXED, __HIP_MEMORY_SCOPE_AGENT) < NSCAN)
            __builtin_amdgcn_s_sleep(2);
        __threadfence();                   // acquire: fresh car
    }
    __syncthreads();

    // ---- phase C: rerun recurrence from carry using register-resident x ----
    const float4 cc = C4[grp];
    float4 s0 = car4[(size_t)chunk * G4 + grp];
    sx = s0.x; sy = s0.y; sz = s0.z; sw = s0.w;

    #pragma unroll
    for (int t = 0; t < CL; ++t) {
        sx = fmaf(a.x, sx, b.x * xr[t].x);
        sy = fmaf(a.y, sy, b.y * xr[t].y);
        sz = fmaf(a.z, sz, b.z * xr[t].z);
        sw = fmaf(a.w, sw, b.w * xr[t].w);
        f32x4 o;
        o.x = fast_tanh(cc.x * sx);
        o.y = fast_tanh(cc.y * sy);
        o.z = fast_tanh(cc.z * sz);
        o.w = fast_tanh(cc.w * sw);
        __builtin_nontemporal_store(o, (f32x4*)&y4[base + (size_t)t * G4]);  // y never re-read
    }
}

// ==================== fallback 3-kernel path (if ws too small for counters) ====================
__global__ __launch_bounds__(256) void mamba_p1(
    const float4* __restrict__ x4, const float4* __restrict__ A4,
    const float4* __restrict__ B4, float4* __restrict__ loc4)
{
    int lin = blockIdx.x * 256 + threadIdx.x;
    int chunk = lin >> 9, grp = lin & (G4 - 1);
    float4 a = A4[grp], b = B4[grp];
    float sx = 0.f, sy = 0.f, sz = 0.f, sw = 0.f;
    const float4* xp = x4 + (size_t)chunk * CL * G4 + grp;
    #pragma unroll
    for (int t = 0; t < CL; ++t) {
        float4 v = xp[(size_t)t * G4];
        sx = fmaf(a.x, sx, b.x * v.x); sy = fmaf(a.y, sy, b.y * v.y);
        sz = fmaf(a.z, sz, b.z * v.z); sw = fmaf(a.w, sw, b.w * v.w);
    }
    loc4[(size_t)chunk * G4 + grp] = make_float4(sx, sy, sz, sw);
}

__global__ __launch_bounds__(64) void mamba_p2(
    const float* __restrict__ A, const float* __restrict__ loc, float* __restrict__ car)
{
    int ch = blockIdx.x * 64 + threadIdx.x;
    float p = A[ch];
    #pragma unroll
    for (int i = 0; i < 5; ++i) p *= p;
    float c = 0.f;
    for (int c0 = 0; c0 < NC; c0 += 64) {
        float lv[64];
        #pragma unroll
        for (int k = 0; k < 64; ++k) lv[k] = loc[(size_t)(c0 + k) * DD + ch];
        #pragma unroll
        for (int k = 0; k < 64; ++k) {
            car[(size_t)(c0 + k) * DD + ch] = c;
            c = fmaf(p, c, lv[k]);
        }
    }
}

__global__ __launch_bounds__(256) void mamba_p3(
    const float4* __restrict__ x4, const float4* __restrict__ A4,
    const float4* __restrict__ B4, const float4* __restrict__ C4,
    const float4* __restrict__ car4, float4* __restrict__ y4)
{
    int lin = blockIdx.x * 256 + threadIdx.x;
    int chunk = lin >> 9, grp = lin & (G4 - 1);
    float4 a = A4[grp], b = B4[grp], c = C4[grp];
    float4 s0 = car4[(size_t)chunk * G4 + grp];
    float sx = s0.x, sy = s0.y, sz = s0.z, sw = s0.w;
    const float4* xp = x4 + (size_t)chunk * CL * G4 + grp;
    float4*       yp = y4 + (size_t)chunk * CL * G4 + grp;
    #pragma unroll 8
    for (int t = 0; t < CL; ++t) {
        float4 v = xp[(size_t)t * G4];
        sx = fmaf(a.x, sx, b.x * v.x); sy = fmaf(a.y, sy, b.y * v.y);
        sz = fmaf(a.z, sz, b.z * v.z); sw = fmaf(a.w, sw, b.w * v.w);
        yp[(size_t)t * G4] = make_float4(fast_tanh(c.x * sx), fast_tanh(c.y * sy),
                                         fast_tanh(c.z * sz), fast_tanh(c.w * sw));
    }
}

extern "C" void kernel_launch(void* const* d_in, const int* in_sizes, int n_in,
                              void* d_out, int out_size, void* d_ws, size_t ws_size,
                              hipStream_t stream)
{
    const float4* x4 = (const float4*)d_in[0];
    const float4* A4 = (const float4*)d_in[1];
    const float4* B4 = (const float4*)d_in[2];
    const float4* C4 = (const float4*)d_in[3];
    float4* y4 = (float4*)d_out;

    float4* loc4 = (float4*)d_ws;                       // 2 MiB
    float4* car4 = loc4 + (size_t)NC * G4;              // 2 MiB
    const size_t body = (size_t)NC * DD * 4 * 2;        // 4 MiB

    if (ws_size >= body + 16) {
        unsigned* cnt = (unsigned*)((char*)d_ws + body);
        (void)hipMemsetAsync(cnt, 0, 16, stream);       // counters must start at 0 each call
        mamba_fused<<<NBLK, 256, 0, stream>>>(x4, A4, B4, C4, loc4, car4, cnt, y4);
    } else {
        const float* Af  = (const float*)d_in[1];
        float* locf = (float*)loc4;
        float* carf = (float*)car4;
        const int nthreads = NC * G4;
        mamba_p1<<<nthreads / 256, 256, 0, stream>>>(x4, A4, B4, loc4);
        mamba_p2<<<DD / 64, 64, 0, stream>>>(Af, locf, carf);
        mamba_p3<<<nthreads / 256, 256, 0, stream>>>(x4, A4, B4, C4, car4, y4);
    }
}